// Round 4
// baseline (148919.324 us; speedup 1.0000x reference)
//
#include <hip/hip_runtime.h>
#include <cstdint>

typedef __bf16 bf16;
typedef bf16 bf16x8 __attribute__((ext_vector_type(8)));
typedef bf16 bf16x4 __attribute__((ext_vector_type(4)));
typedef float f32x4 __attribute__((ext_vector_type(4)));

#define DI __device__ __forceinline__

DI float sigmoidf_(float x) { return 1.0f / (1.0f + __expf(-x)); }
DI float tanhf_(float x)    { return 1.0f - 2.0f / (__expf(2.0f * x) + 1.0f); }

// ---------------------------------------------------------------------------
// Grid-wide barrier (device-scope; safe across XCDs via agent fences).
// ---------------------------------------------------------------------------
DI void gsync(int* bar)
{
  __syncthreads();
  if (threadIdx.x == 0) {
    __threadfence();
    int gen = __hip_atomic_load(bar + 1, __ATOMIC_RELAXED, __HIP_MEMORY_SCOPE_AGENT);
    if (__hip_atomic_fetch_add(bar, 1, __ATOMIC_ACQ_REL, __HIP_MEMORY_SCOPE_AGENT)
        == (int)gridDim.x - 1) {
      __hip_atomic_store(bar, 0, __ATOMIC_RELAXED, __HIP_MEMORY_SCOPE_AGENT);
      __hip_atomic_store(bar + 1, gen + 1, __ATOMIC_RELEASE, __HIP_MEMORY_SCOPE_AGENT);
    } else {
      while (__hip_atomic_load(bar + 1, __ATOMIC_ACQUIRE, __HIP_MEMORY_SCOPE_AGENT) == gen)
        __builtin_amdgcn_s_sleep(8);
    }
    __threadfence();
  }
  __syncthreads();
}

// ---------------------------------------------------------------------------
// Cooperative act-tile stage: 128 rows x 128 k-elems (src stride 512) into
// LDS with padded stride 136 (bank-conflict-free for the b128 reads).
// 8 independent 16B loads per thread -> deep MLP on the act stream.
// ---------------------------------------------------------------------------
DI void stage_tile(bf16* __restrict__ dst, const bf16* __restrict__ src, int tid)
{
  bf16x8 tmp[8];
#pragma unroll
  for (int r = 0; r < 8; ++r) {
    int s = tid + r * 256;
    tmp[r] = *(const bf16x8*)(src + (s >> 4) * 512 + (s & 15) * 8);
  }
#pragma unroll
  for (int r = 0; r < 8; ++r) {
    int s = tid + r * 256;
    *(bf16x8*)(dst + (s >> 4) * 136 + (s & 15) * 8) = tmp[r];
  }
}

// ---------------------------------------------------------------------------
// Staged GEMM: acc[8] (16 n-rows/wave x 128 b) over K=1024 = A0(512)+A1(512).
// Weights streamed via explicit depth-8 prefetch ring; act via LDS dbuf.
// K-summation order identical to the round-1/2 kernels (absmax-stable).
// ---------------------------------------------------------------------------
DI void gemm_staged(f32x4 acc[8], const bf16* __restrict__ wrow,
                    const bf16* __restrict__ A0, const bf16* __restrict__ A1,
                    bf16* __restrict__ sbuf, int tid)
{
  const int lane = tid & 63;
  const int q = lane >> 4, col = lane & 15;
  const bf16* wp = wrow + q * 8;
  bf16x8 wb[8];
#pragma unroll
  for (int i = 0; i < 8; ++i) wb[i] = *(const bf16x8*)(wp + i * 32);
  stage_tile(sbuf, A0, tid);
  __syncthreads();
#pragma unroll
  for (int c = 0; c < 8; ++c) {
    if (c < 7) {
      const bf16* src = (c + 1 < 4) ? A0 + (c + 1) * 128 : A1 + (c - 3) * 128;
      stage_tile(sbuf + ((c + 1) & 1) * 17408, src, tid);
    }
    const bf16* rb = sbuf + (c & 1) * 17408;
#pragma unroll
    for (int ki = 0; ki < 4; ++ki) {
      const int gi = c * 4 + ki;
      bf16x8 wcur = wb[gi & 7];
      if (gi + 8 < 32) wb[gi & 7] = *(const bf16x8*)(wp + (gi + 8) * 32);
#pragma unroll
      for (int bt = 0; bt < 8; ++bt) {
        bf16x8 af = *(const bf16x8*)(rb + (bt * 16 + col) * 136 + ki * 32 + q * 8);
        acc[bt] = __builtin_amdgcn_mfma_f32_16x16x32_bf16(wcur, af, acc[bt], 0, 0, 0);
      }
    }
    __syncthreads();
  }
}

// --------------------------- LSTM level (vb in [0,96)) ---------------------
DI void d_lstm(int vb, int tid,
               const bf16* __restrict__ A0, long a0ss,
               const bf16* __restrict__ A1,
               const bf16* __restrict__ W,
               const float* __restrict__ bias,
               const float* __restrict__ csR,
               float* __restrict__ csW,
               bf16* __restrict__ hOut, bf16* __restrict__ sbuf)
{
  const int bx = vb & 31, ax = vb >> 5;
  const int lane = tid & 63, wave = tid >> 6;
  const int q = lane >> 4, col = lane & 15;
  const int n0 = bx * 64 + wave * 16;
  const bf16* wrow = W + (long)ax * 10485760L + (long)(n0 + col) * 1024;
  f32x4 acc[8] = {};
  gemm_staged(acc, wrow, A0 + (long)ax * a0ss, A1 + (long)ax * 65536, sbuf, tid);
  const int o = (n0 >> 2) + q;
  const float* bi = bias + (long)ax * 10240;
  float b0f = bi[o], b1f = bi[512 + o], b2f = bi[1024 + o], b3f = bi[1536 + o];
  const float* csr = csR + (long)ax * 65536;
  float* csw = csW + (long)ax * 65536;
  bf16* hl = hOut + (long)ax * 65536;
#pragma unroll
  for (int bt = 0; bt < 8; ++bt) {
    int b = bt * 16 + col;
    float ig = sigmoidf_(acc[bt][0] + b0f);
    float fg = sigmoidf_(acc[bt][1] + b1f);
    float gg = tanhf_   (acc[bt][2] + b2f);
    float og = sigmoidf_(acc[bt][3] + b3f);
    long idx = (long)b * 512 + o;
    float cn = fg * csr[idx] + ig * gg;
    csw[idx] = cn;
    hl[idx] = (bf16)(og * tanhf_(cn));
  }
}

// --------------------------- cell_fn gates (vb in [0,480)) -----------------
DI void d_cell(int vb, int tid,
               const bf16* __restrict__ hg, const bf16* __restrict__ hsC,
               const bf16* __restrict__ Wg, const float* __restrict__ bgp,
               const float* __restrict__ csC,
               bf16* __restrict__ icat, bf16* __restrict__ ccat,
               bf16* __restrict__ sbuf)
{
  const int bx = vb & 31, sl = vb >> 5;
  const int l = sl / 3, a = sl - l * 3;
  const int lane = tid & 63, wave = tid >> 6;
  const int q = lane >> 4, col = lane & 15;
  const int n0 = bx * 64 + wave * 16;
  const bf16* wrow = Wg + (long)sl * 2097152L + (long)(n0 + col) * 1024;
  f32x4 acc[8] = {};
  gemm_staged(acc, wrow, hg, hsC + (long)sl * 65536, sbuf, tid);
  const int z = (n0 >> 2) + q;
  const float* bgl = bgp + (long)sl * 1536;
  float g0 = bgl[z], g1 = bgl[512 + z], g2 = bgl[1024 + z];
  const float* csl = csC + (long)sl * 65536;
  const long obase = (long)l * 196608 + (long)a * 512 + z;
#pragma unroll
  for (int bt = 0; bt < 8; ++bt) {
    int b = bt * 16 + col;
    float ig = sigmoidf_(acc[bt][0] + g0);
    float fg = sigmoidf_(acc[bt][1] + g1);
    float gg = tanhf_   (acc[bt][2] + g2);
    float sc = csl[(long)b * 512 + z];
    float icl = ig * sc;
    float ccl = fg * gg + icl;
    long oi = obase + (long)b * 1536;
    icat[oi] = (bf16)icl;
    ccat[oi] = (bf16)ccl;
  }
}

// ----------------------- t1/t2 dual GEMM (vb in [0,80)) --------------------
// vb = bx(8) x by(2) x l(5), NB=4 dual, K=1536; weight ring depth 8.
DI void d_tg(int vb, int tid,
             const bf16* __restrict__ icat, const bf16* __restrict__ ccat,
             const bf16* __restrict__ Wt, const float* __restrict__ bilc,
             float* __restrict__ t1s, float* __restrict__ t2s)
{
  const int bx = vb & 7, by = (vb >> 3) & 1, l = vb >> 4;
  const int lane = tid & 63, wave = tid >> 6;
  const int q = lane >> 4, col = lane & 15;
  const int n0 = bx * 64 + wave * 16;
  const int b0 = by * 64;
  const bf16* wp = Wt + (long)l * 786432L + (long)(n0 + col) * 1536 + q * 8;
  const bf16* ic = icat + (long)l * 196608 + (long)b0 * 1536 + q * 8;
  const bf16* cc = ccat + (long)l * 196608 + (long)b0 * 1536 + q * 8;
  bf16x8 wb[8];
#pragma unroll
  for (int i = 0; i < 8; ++i) wb[i] = *(const bf16x8*)(wp + (long)i * 32);
  f32x4 a1[4] = {}, a2[4] = {};
#pragma unroll 8
  for (int ki = 0; ki < 48; ++ki) {
    bf16x8 wcur = wb[ki & 7];
    if (ki < 40) wb[ki & 7] = *(const bf16x8*)(wp + (long)(ki + 8) * 32);
    const long k = (long)ki * 32;
#pragma unroll
    for (int bt = 0; bt < 4; ++bt) {
      long ro = (long)(bt * 16 + col) * 1536 + k;
      bf16x8 f1 = *(const bf16x8*)(ic + ro);
      bf16x8 f2 = *(const bf16x8*)(cc + ro);
      a1[bt] = __builtin_amdgcn_mfma_f32_16x16x32_bf16(wcur, f1, a1[bt], 0, 0, 0);
      a2[bt] = __builtin_amdgcn_mfma_f32_16x16x32_bf16(wcur, f2, a2[bt], 0, 0, 0);
    }
  }
  const int yb = n0 + 4 * q;
  const float* bl = bilc + (long)l * 1536;
  f32x4 bs;
#pragma unroll
  for (int r = 0; r < 4; ++r) bs[r] = bl[yb + r] + bl[512 + yb + r] + bl[1024 + yb + r];
#pragma unroll
  for (int bt = 0; bt < 4; ++bt) {
    int b = b0 + bt * 16 + col;
    f32x4 v1 = a1[bt] + bs, v2 = a2[bt] + bs;
    *(f32x4*)(t1s + ((long)l * 128 + b) * 512 + yb) = v1;
    *(f32x4*)(t2s + ((long)l * 128 + b) * 512 + yb) = v2;
  }
}

// ------------------ softmax/sigmoid combine (vb in [0,40)) -----------------
DI void d_comb(int vb, int tid,
               const float* __restrict__ t1s, const float* __restrict__ t2s,
               bf16* __restrict__ cat)
{
  const int bgrp = vb & 7, l = vb >> 3;
  const int lane = tid & 63, wave = tid >> 6;
#pragma unroll
  for (int i = 0; i < 4; ++i) {
    const int b = bgrp * 16 + wave * 4 + i;
    const float* r1 = t1s + ((long)l * 128 + b) * 512 + lane * 8;
    const float* r2 = t2s + ((long)l * 128 + b) * 512 + lane * 8;
    f32x4 u0 = *(const f32x4*)r1, u1 = *(const f32x4*)(r1 + 4);
    float mx = u0[0];
#pragma unroll
    for (int j = 1; j < 4; ++j) mx = fmaxf(mx, u0[j]);
#pragma unroll
    for (int j = 0; j < 4; ++j) mx = fmaxf(mx, u1[j]);
    for (int d = 32; d > 0; d >>= 1) mx = fmaxf(mx, __shfl_xor(mx, d, 64));
    float e[8], ss = 0.f;
#pragma unroll
    for (int j = 0; j < 4; ++j) { e[j] = __expf(u0[j] - mx); ss += e[j]; }
#pragma unroll
    for (int j = 0; j < 4; ++j) { e[4 + j] = __expf(u1[j] - mx); ss += e[4 + j]; }
    for (int d = 32; d > 0; d >>= 1) ss += __shfl_xor(ss, d, 64);
    float inv = 1.0f / ss;
    f32x4 w0 = *(const f32x4*)r2, w1 = *(const f32x4*)(r2 + 4);
    bf16x8 ob;
#pragma unroll
    for (int j = 0; j < 4; ++j) ob[j]     = (bf16)(sigmoidf_(w0[j]) * e[j]     * inv);
#pragma unroll
    for (int j = 0; j < 4; ++j) ob[4 + j] = (bf16)(sigmoidf_(w1[j]) * e[4 + j] * inv);
    *(bf16x8*)(cat + (long)b * 2560 + l * 512 + lane * 8) = ob;
  }
}

// ------------- single_li + per-step linear, fused (vb in [0,8)) ------------
DI void d_slgfin(int vb, int tid,
                 const bf16* __restrict__ cat, const bf16* __restrict__ Wsl,
                 const float* __restrict__ bsl, const float* __restrict__ wlin,
                 const float* __restrict__ blin,
                 bf16* __restrict__ hg, float* __restrict__ out, int tc,
                 float* __restrict__ lds)
{
  const int lane = tid & 63, wave = tid >> 6;
  const int q = lane >> 4, col = lane & 15;
  const int b0 = vb * 16;
  const int nh = wave & 1, kh = wave >> 1;
  const bf16* arow  = cat + (long)(b0 + col) * 2560 + kh * 1280 + q * 8;
  const bf16* wbase = Wsl + (long)(nh * 256 + col) * 2560 + kh * 1280 + q * 8;
  f32x4 acc[16] = {};
#pragma unroll 2
  for (int ki = 0; ki < 40; ++ki) {
    const long k = ki * 32;
    bf16x8 af = *(const bf16x8*)(arow + k);
#pragma unroll
    for (int j = 0; j < 16; ++j) {
      bf16x8 wf = *(const bf16x8*)(wbase + (long)j * 40960 + k);
      acc[j] = __builtin_amdgcn_mfma_f32_16x16x32_bf16(wf, af, acc[j], 0, 0, 0);
    }
  }
#pragma unroll
  for (int j = 0; j < 16; ++j) {
    int n = nh * 256 + j * 16 + q * 4;
    *(f32x4*)(lds + (kh * 16 + col) * 516 + n) = acc[j];
  }
  __syncthreads();
#pragma unroll
  for (int i = 0; i < 4; ++i) {
    const int bi = wave * 4 + i;
    const int n0 = lane * 8;
    const float* p0 = lds + bi * 516 + n0;
    const float* p1 = lds + (16 + bi) * 516 + n0;
    f32x4 s0 = *(const f32x4*)p0 + *(const f32x4*)p1 + *(const f32x4*)(bsl + n0);
    f32x4 s1 = *(const f32x4*)(p0 + 4) + *(const f32x4*)(p1 + 4)
             + *(const f32x4*)(bsl + n0 + 4);
    bf16x8 hb;
#pragma unroll
    for (int j = 0; j < 4; ++j) { hb[j] = (bf16)s0[j]; hb[4 + j] = (bf16)s1[j]; }
    *(bf16x8*)(hg + (long)(b0 + bi) * 512 + n0) = hb;
    const float* wl = wlin + (long)tc * 512 + n0;
    f32x4 w0 = *(const f32x4*)wl, w1 = *(const f32x4*)(wl + 4);
    float dot = s0[0]*w0[0] + s0[1]*w0[1] + s0[2]*w0[2] + s0[3]*w0[3]
              + s1[0]*w1[0] + s1[1]*w1[1] + s1[2]*w1[2] + s1[3]*w1[3];
    for (int d = 32; d > 0; d >>= 1) dot += __shfl_xor(dot, d, 64);
    if (lane == 0) out[tc * 128 + (b0 + bi)] = dot + blin[tc];
  }
}

// ------------------------- persistent pipelined kernel ---------------------
// grid 512 x 256thr: 2 blocks/CU co-resident (LDS 69.6KB, VGPR<=256), 8 w/CU.
__global__ __launch_bounds__(256, 2) void k_persist(
    const bf16* __restrict__ xbf, const bf16* __restrict__ Wcat,
    const float* __restrict__ b_l, const bf16* __restrict__ Wg,
    const float* __restrict__ bg, const bf16* __restrict__ Wt,
    const float* __restrict__ bilc, const bf16* __restrict__ Wslb,
    const float* __restrict__ bsl, const float* __restrict__ Wlin,
    const float* __restrict__ blin,
    bf16* hs0, bf16* hs1, bf16* hgb, float* cs0, float* cs1,
    bf16* icat, bf16* ccat, float* t1s, float* t2s, bf16* catb,
    float* out, int* bar)
{
  __shared__ __align__(16) char smemraw[69632];   // act dbuf (2x34816B) | fin lds
  bf16* sbuf = (bf16*)smemraw;
  float* flds = (float*)smemraw;
  const int tid = threadIdx.x;
  for (int s = 0; s < 65; ++s) {
    const bool doL = s < 64, doC = s > 0;
    const int t = doL ? s : 63, tc = doC ? s - 1 : 0;
    const bf16*  hsR = (t & 1) ? hs1 : hs0;
    bf16*        hsW = (t & 1) ? hs0 : hs1;
    const float* csR = (t & 1) ? cs1 : cs0;
    float*       csW = (t & 1) ? cs0 : cs1;
    const bf16*  hsC = (tc & 1) ? hs0 : hs1;
    const float* csC = (tc & 1) ? cs0 : cs1;
    for (int sl = 0; sl < 5; ++sl) {
      const int nL = doL ? 96 : 0;
      const int nC = doC ? ((sl < 2) ? 240 : (sl == 2) ? 80 : (sl == 3) ? 40 : 8) : 0;
      const bf16* A0 = (sl == 0) ? xbf + (long)t * 65536
                                 : hsW + (long)(sl - 1) * 196608;
      const long a0ss = (sl == 0) ? 0L : 65536L;
      for (int vb = blockIdx.x; vb < nL + nC; vb += (int)gridDim.x) {
        if (vb < nL) {
          d_lstm(vb, tid, A0, a0ss, hsR + (long)sl * 196608,
                 Wcat + (long)sl * 2097152, b_l + sl * 2048,
                 csR + (long)sl * 196608, csW + (long)sl * 196608,
                 hsW + (long)sl * 196608, sbuf);
        } else {
          const int cv = vb - nL;
          if (sl == 0)      d_cell(cv,       tid, hgb, hsC, Wg, bg, csC, icat, ccat, sbuf);
          else if (sl == 1) d_cell(cv + 240, tid, hgb, hsC, Wg, bg, csC, icat, ccat, sbuf);
          else if (sl == 2) d_tg  (cv, tid, icat, ccat, Wt, bilc, t1s, t2s);
          else if (sl == 3) d_comb(cv, tid, t1s, t2s, catb);
          else d_slgfin(cv, tid, catb, Wslb, bsl, Wlin, blin, hgb, out, tc, flds);
        }
      }
      gsync(bar);
    }
  }
}

// ------------------------- weight conversion kernels -----------------------
__global__ __launch_bounds__(256) void cvt_wxh(const float* __restrict__ Wx,
    const float* __restrict__ Wh, bf16* __restrict__ dst)
{
  long idx = ((long)blockIdx.x * 256 + threadIdx.x) * 4;   // [al][n][k], n=4o+g
  int k = (int)(idx & 1023);
  int n = (int)((idx >> 10) & 2047);
  long al = idx >> 21;                                     // a*5+l
  int g = n & 3, o = n >> 2;
  const float* src = (k < 512)
      ? Wx + ((al * 4 + g) * 512 + o) * 512 + k
      : Wh + ((al * 4 + g) * 512 + o) * 512 + (k - 512);
  f32x4 v = *(const f32x4*)src;
  bf16x4 ov;
#pragma unroll
  for (int j = 0; j < 4; ++j) ov[j] = (bf16)v[j];
  *(bf16x4*)(dst + idx) = ov;
}

__global__ __launch_bounds__(256) void cvt_wg(const float* __restrict__ Wg_h,
    const float* __restrict__ Wg_p, bf16* __restrict__ dst)
{
  long idx = ((long)blockIdx.x * 256 + threadIdx.x) * 4;   // [la][n=4z+g][k], g==3 pad
  int k = (int)(idx & 1023);
  int n = (int)((idx >> 10) & 2047);
  long la = idx >> 21;                                     // l*3+a
  int g = n & 3, z = n >> 2;
  f32x4 v = {0, 0, 0, 0};
  if (g < 3) {
    const float* src = (k < 512)
        ? Wg_h + ((la * 3 + g) * 512 + z) * 512 + k
        : Wg_p + ((la * 3 + g) * 512 + z) * 512 + (k - 512);
    v = *(const f32x4*)src;
  }
  bf16x4 ov;
#pragma unroll
  for (int j = 0; j < 4; ++j) ov[j] = (bf16)v[j];
  *(bf16x4*)(dst + idx) = ov;
}

__global__ __launch_bounds__(256) void cvt_wt(const float* __restrict__ Wilc,
                                              bf16* __restrict__ dst)
{
  long idx = (long)blockIdx.x * 256 + threadIdx.x;         // [l][y][k=a*512+z]
  int k = (int)(idx % 1536);
  long rest = idx / 1536;
  int y = (int)(rest & 511);
  int l = (int)(rest >> 9);
  int a = k >> 9, z = k & 511;
  dst[idx] = (bf16)Wilc[(((long)l * 3 + a) * 512 + z) * 512 + y];
}

__global__ __launch_bounds__(256) void k_cast(const float* __restrict__ s,
                                              bf16* __restrict__ d)
{
  long i = ((long)blockIdx.x * 256 + threadIdx.x) * 4;
  f32x4 v = *(const f32x4*)(s + i);
  bf16x4 ov;
#pragma unroll
  for (int j = 0; j < 4; ++j) ov[j] = (bf16)v[j];
  *(bf16x4*)(d + i) = ov;
}

__global__ __launch_bounds__(256) void k_zero(uint4* __restrict__ p, long n)
{
  long i = (long)blockIdx.x * 256 + threadIdx.x;
  if (i < n) p[i] = make_uint4(0, 0, 0, 0);
}

// ---------------------------------------------------------------------------
extern "C" void kernel_launch(void* const* d_in, const int* in_sizes, int n_in,
                              void* d_out, int out_size, void* d_ws, size_t ws_size,
                              hipStream_t stream)
{
  const float* x    = (const float*)d_in[0];
  const float* Wx   = (const float*)d_in[1];
  const float* Wh   = (const float*)d_in[2];
  const float* b_l  = (const float*)d_in[3];
  const float* Wg_h = (const float*)d_in[4];
  const float* Wg_p = (const float*)d_in[5];
  const float* bg   = (const float*)d_in[6];
  const float* Wilc = (const float*)d_in[7];
  const float* bilc = (const float*)d_in[8];
  const float* Wsl  = (const float*)d_in[9];
  const float* bsl  = (const float*)d_in[10];
  const float* Wlin = (const float*)d_in[11];
  const float* blin = (const float*)d_in[12];
  float* out = (float*)d_out;

  char* w = (char*)d_ws;
  auto alloc = [&](long bytes) { char* p = w; w += (bytes + 255) & ~255L; return p; };
  bf16* Wcat = (bf16*)alloc(31457280L * 2);   // [a][l][2048][1024]
  bf16* Wg   = (bf16*)alloc(31457280L * 2);   // [l*3+a][2048][1024]
  bf16* Wt   = (bf16*)alloc(3932160L * 2);    // [l][512][1536]
  bf16* Wslb = (bf16*)alloc(1310720L * 2);    // [512][2560]
  bf16* xbf  = (bf16*)alloc(4194304L * 2);    // [t][b][512]
  char* zbase = w;
  bf16* hs0  = (bf16*)alloc(983040L * 2);     // [l][a][b][512] ping
  bf16* hs1  = (bf16*)alloc(983040L * 2);     // pong
  bf16* hgb  = (bf16*)alloc(65536L * 2);      // [b][512]
  float* cs0 = (float*)alloc(983040L * 4);    // [l][a][b][512] ping
  float* cs1 = (float*)alloc(983040L * 4);    // pong
  int*  bar  = (int*)alloc(256);              // grid barrier {count, gen}
  long zbytes = w - zbase;
  bf16* icat = (bf16*)alloc(983040L * 2);     // [l][b][1536]
  bf16* ccat = (bf16*)alloc(983040L * 2);
  float* t1s = (float*)alloc(327680L * 4);    // [l][b][512]
  float* t2s = (float*)alloc(327680L * 4);
  bf16* catb = (bf16*)alloc(327680L * 2);     // [b][2560]
  (void)ws_size; (void)n_in; (void)in_sizes; (void)out_size;

  // --- setup (runs every call; ws is re-poisoned by the harness) ---
  cvt_wxh<<<30720, 256, 0, stream>>>(Wx, Wh, Wcat);
  cvt_wg <<<30720, 256, 0, stream>>>(Wg_h, Wg_p, Wg);
  cvt_wt <<<15360, 256, 0, stream>>>(Wilc, Wt);
  k_cast <<<1280,  256, 0, stream>>>(Wsl, Wslb);
  k_cast <<<4096,  256, 0, stream>>>(x, xbf);
  {
    long n16 = zbytes / 16;
    k_zero<<<(int)((n16 + 255) / 256), 256, 0, stream>>>((uint4*)zbase, n16);
  }

  // --- one persistent kernel runs the whole 64-step recurrence ---
  k_persist<<<512, 256, 0, stream>>>(
      xbf, Wcat, b_l, Wg, bg, Wt, bilc, Wslb, bsl, Wlin, blin,
      hs0, hs1, hgb, cs0, cs1, icat, ccat, t1s, t2s, catb, out, bar);
}

// Round 5
// 14355.501 us; speedup vs baseline: 10.3737x; 10.3737x over previous
//
#include <hip/hip_runtime.h>
#include <cstdint>

typedef __bf16 bf16;
typedef bf16 bf16x8 __attribute__((ext_vector_type(8)));
typedef bf16 bf16x4 __attribute__((ext_vector_type(4)));
typedef float f32x4 __attribute__((ext_vector_type(4)));

#define DI __device__ __forceinline__

DI float sigmoidf_(float x) { return 1.0f / (1.0f + __expf(-x)); }
DI float tanhf_(float x)    { return 1.0f - 2.0f / (__expf(2.0f * x) + 1.0f); }

// ---------------------------------------------------------------------------
// GEMM core: C[n][b] += sum_k W[n][k] * act[b][k]   (MFMA 16x16x32 bf16)
//   A-op (W): m=lane&15, k=(lane>>4)*8+j ; B-op (act): n=lane&15, same k
//   C/D: col(=b)=lane&15, row(=n)=(lane>>4)*4+reg
// K and STRIDE are compile-time so the loop fully unrolls -> the compiler
// batches independent global loads (deep MLP) instead of a serial chain.
// ---------------------------------------------------------------------------
template<int NB, int K, int STRIDE>
DI void mmK(f32x4* acc, const bf16* __restrict__ wrow,
            const bf16* __restrict__ act, int q, int col)
{
#pragma unroll
  for (int ki = 0; ki < K / 32; ++ki) {
    const int k = ki * 32 + q * 8;
    bf16x8 wf = *(const bf16x8*)(wrow + k);
#pragma unroll
    for (int bt = 0; bt < NB; ++bt) {
      bf16x8 af = *(const bf16x8*)(act + (long)(bt * 16 + col) * STRIDE + k);
      acc[bt] = __builtin_amdgcn_mfma_f32_16x16x32_bf16(wf, af, acc[bt], 0, 0, 0);
    }
  }
}

template<int NB, int K, int STRIDE>
DI void mmK_dual(f32x4* x1, f32x4* x2, const bf16* __restrict__ wrow,
                 const bf16* __restrict__ act1, const bf16* __restrict__ act2,
                 int q, int col)
{
#pragma unroll
  for (int ki = 0; ki < K / 32; ++ki) {
    const int k = ki * 32 + q * 8;
    bf16x8 wf = *(const bf16x8*)(wrow + k);
#pragma unroll
    for (int bt = 0; bt < NB; ++bt) {
      long ro = (long)(bt * 16 + col) * STRIDE + k;
      bf16x8 a1 = *(const bf16x8*)(act1 + ro);
      bf16x8 a2 = *(const bf16x8*)(act2 + ro);
      x1[bt] = __builtin_amdgcn_mfma_f32_16x16x32_bf16(wf, a1, x1[bt], 0, 0, 0);
      x2[bt] = __builtin_amdgcn_mfma_f32_16x16x32_bf16(wf, a2, x2[bt], 0, 0, 0);
    }
  }
}

// --------------------------- LSTM level (device part) ----------------------
// bid in [0,384): bx=ntile64(32) x by=batch-quarter(4) x axis(3). NB=2.
// Wcat layout [a][l][n=4o+g][k(0:512 Wx | 512:1024 Wh)].
DI void d_lstm(int bid, int tid,
               const bf16* __restrict__ A0, long a0ss,
               const bf16* __restrict__ A1,
               const bf16* __restrict__ W,
               const float* __restrict__ bias,
               const float* __restrict__ csR,
               float* __restrict__ csW,
               bf16* __restrict__ hOut)
{
  const int bx = bid & 31, by = (bid >> 5) & 3, ax = bid >> 7;
  const int lane = tid & 63, wave = tid >> 6;
  const int q = lane >> 4, col = lane & 15;
  const int n0 = bx * 64 + wave * 16;
  const int b0 = by * 32;
  const bf16* wrow = W + (long)ax * 10485760L + (long)(n0 + col) * 1024;
  const bf16* a0 = A0 + (long)ax * a0ss + (long)b0 * 512;
  const bf16* a1 = A1 + (long)ax * 65536 + (long)b0 * 512;
  f32x4 acc[2] = {};
  mmK<2, 512, 512>(acc, wrow,       a0, q, col);
  mmK<2, 512, 512>(acc, wrow + 512, a1, q, col);
  const int o = (n0 >> 2) + q;
  const float* bi = bias + (long)ax * 10240;
  float b0f = bi[o], b1f = bi[512 + o], b2f = bi[1024 + o], b3f = bi[1536 + o];
  const float* csr = csR + (long)ax * 65536;
  float* csw = csW + (long)ax * 65536;
  bf16* hl = hOut + (long)ax * 65536;
#pragma unroll
  for (int bt = 0; bt < 2; ++bt) {
    int b = b0 + bt * 16 + col;
    float ig = sigmoidf_(acc[bt][0] + b0f);
    float fg = sigmoidf_(acc[bt][1] + b1f);
    float gg = tanhf_   (acc[bt][2] + b2f);
    float og = sigmoidf_(acc[bt][3] + b3f);
    long idx = (long)b * 512 + o;
    float cn = fg * csr[idx] + ig * gg;
    csw[idx] = cn;
    hl[idx] = (bf16)(og * tanhf_(cn));
  }
}

// --------------------------- cell_fn gates (device part) -------------------
// bid in [0,960): bx=ntile64(32) x by=batch-half(2) x sl=l*3+a(15). NB=4.
DI void d_cell(int bid, int tid,
               const bf16* __restrict__ hg, const bf16* __restrict__ hsC,
               const bf16* __restrict__ Wg, const float* __restrict__ bgp,
               const float* __restrict__ csC,
               bf16* __restrict__ icat, bf16* __restrict__ ccat)
{
  const int bx = bid & 31, by = (bid >> 5) & 1, sl = bid >> 6;
  const int l = sl / 3, a = sl - l * 3;
  const int lane = tid & 63, wave = tid >> 6;
  const int q = lane >> 4, col = lane & 15;
  const int n0 = bx * 64 + wave * 16;
  const int b0 = by * 64;
  const bf16* wrow = Wg + (long)sl * 2097152L + (long)(n0 + col) * 1024;
  f32x4 acc[4] = {};
  mmK<4, 512, 512>(acc, wrow,       hg + (long)b0 * 512,                     q, col);
  mmK<4, 512, 512>(acc, wrow + 512, hsC + (long)sl * 65536 + (long)b0 * 512, q, col);
  const int z = (n0 >> 2) + q;
  const float* bgl = bgp + (long)sl * 1536;
  float g0 = bgl[z], g1 = bgl[512 + z], g2 = bgl[1024 + z];
  const float* csl = csC + (long)sl * 65536;
  const long obase = (long)l * 196608 + (long)a * 512 + z;
#pragma unroll
  for (int bt = 0; bt < 4; ++bt) {
    int b = b0 + bt * 16 + col;
    float ig = sigmoidf_(acc[bt][0] + g0);
    float fg = sigmoidf_(acc[bt][1] + g1);
    float gg = tanhf_   (acc[bt][2] + g2);
    float sc = csl[(long)b * 512 + z];
    float icl = ig * sc;
    float ccl = fg * gg + icl;
    long oi = obase + (long)b * 1536;
    icat[oi] = (bf16)icl;
    ccat[oi] = (bf16)ccl;
  }
}

// ----------------------- t1/t2 dual GEMM (device part) ---------------------
// bid in [0,160): bx=ntile64(8) x by=batch-quarter(4) x l(5). NB=2 dual.
DI void d_tg(int bid, int tid,
             const bf16* __restrict__ icat, const bf16* __restrict__ ccat,
             const bf16* __restrict__ Wt, const float* __restrict__ bilc,
             float* __restrict__ t1s, float* __restrict__ t2s)
{
  const int bx = bid & 7, by = (bid >> 3) & 3, l = bid >> 5;
  const int lane = tid & 63, wave = tid >> 6;
  const int q = lane >> 4, col = lane & 15;
  const int n0 = bx * 64 + wave * 16;
  const int b0 = by * 32;
  const bf16* wrow = Wt + (long)l * 786432L + (long)(n0 + col) * 1536;
  const bf16* ic = icat + (long)l * 196608 + (long)b0 * 1536;
  const bf16* cc = ccat + (long)l * 196608 + (long)b0 * 1536;
  f32x4 a1[2] = {}, a2[2] = {};
  mmK_dual<2, 1536, 1536>(a1, a2, wrow, ic, cc, q, col);
  const int yb = n0 + 4 * q;
  const float* bl = bilc + (long)l * 1536;
  f32x4 bs;
#pragma unroll
  for (int r = 0; r < 4; ++r) bs[r] = bl[yb + r] + bl[512 + yb + r] + bl[1024 + yb + r];
#pragma unroll
  for (int bt = 0; bt < 2; ++bt) {
    int b = b0 + bt * 16 + col;
    f32x4 v1 = a1[bt] + bs, v2 = a2[bt] + bs;
    *(f32x4*)(t1s + ((long)l * 128 + b) * 512 + yb) = v1;
    *(f32x4*)(t2s + ((long)l * 128 + b) * 512 + yb) = v2;
  }
}

// ------------------ softmax/sigmoid combine (device part) ------------------
// bid in [0,160): bx=b-tile-of-4(32) x l(5); one (l,b)-row of 512 per wave.
DI void d_comb(int bid, int tid,
               const float* __restrict__ t1s, const float* __restrict__ t2s,
               bf16* __restrict__ cat)
{
  const int bx = bid & 31, l = bid >> 5;
  const int lane = tid & 63, wave = tid >> 6;
  const int b = bx * 4 + wave;
  const float* r1 = t1s + ((long)l * 128 + b) * 512 + lane * 8;
  const float* r2 = t2s + ((long)l * 128 + b) * 512 + lane * 8;
  f32x4 u0 = *(const f32x4*)r1, u1 = *(const f32x4*)(r1 + 4);
  float mx = u0[0];
#pragma unroll
  for (int j = 1; j < 4; ++j) mx = fmaxf(mx, u0[j]);
#pragma unroll
  for (int j = 0; j < 4; ++j) mx = fmaxf(mx, u1[j]);
  for (int d = 32; d > 0; d >>= 1) mx = fmaxf(mx, __shfl_xor(mx, d, 64));
  float e[8], ss = 0.f;
#pragma unroll
  for (int j = 0; j < 4; ++j) { e[j] = __expf(u0[j] - mx); ss += e[j]; }
#pragma unroll
  for (int j = 0; j < 4; ++j) { e[4 + j] = __expf(u1[j] - mx); ss += e[4 + j]; }
  for (int d = 32; d > 0; d >>= 1) ss += __shfl_xor(ss, d, 64);
  float inv = 1.0f / ss;
  f32x4 w0 = *(const f32x4*)r2, w1 = *(const f32x4*)(r2 + 4);
  bf16x8 ob;
#pragma unroll
  for (int j = 0; j < 4; ++j) ob[j]     = (bf16)(sigmoidf_(w0[j]) * e[j]     * inv);
#pragma unroll
  for (int j = 0; j < 4; ++j) ob[4 + j] = (bf16)(sigmoidf_(w1[j]) * e[4 + j] * inv);
  *(bf16x8*)(cat + (long)b * 2560 + l * 512 + lane * 8) = ob;
}

// ---------------- single_li split-K GEMM (device part) ---------------------
// bid in [0,128): bx=ntile64(8) x by=batch-quarter(4) x kc(4). NB=2, K=640.
DI void d_slg(int bid, int tid,
              const bf16* __restrict__ cat, const bf16* __restrict__ Wsl,
              float* __restrict__ hnewp)
{
  const int bx = bid & 7, by = (bid >> 3) & 3, kc = bid >> 5;
  const int lane = tid & 63, wave = tid >> 6;
  const int q = lane >> 4, col = lane & 15;
  const int n0 = bx * 64 + wave * 16;
  const int b0 = by * 32;
  const bf16* wrow = Wsl + (long)(n0 + col) * 2560 + kc * 640;
  const bf16* act = cat + kc * 640 + (long)b0 * 2560;
  f32x4 acc[2] = {};
  mmK<2, 640, 2560>(acc, wrow, act, q, col);
  const int nb = n0 + 4 * q;
#pragma unroll
  for (int bt = 0; bt < 2; ++bt) {
    int b = b0 + bt * 16 + col;
    *(f32x4*)(hnewp + ((long)kc * 128 + b) * 512 + nb) = acc[bt];
  }
}

// -------- finalize: sum K-partials, +bsl, write h_g (bf16) and y ----------
// bid in [0,32): one wave per batch row b.
DI void d_fin(int bid, int tid,
              const float* __restrict__ hnewp, const float* __restrict__ bsl,
              const float* __restrict__ wlin, const float* __restrict__ blin,
              bf16* __restrict__ hg, float* __restrict__ out, int t)
{
  const int lane = tid & 63, wave = tid >> 6;
  const int b = bid * 4 + wave;
  const int h0 = lane * 8;
  f32x4 s0 = {0,0,0,0}, s1 = {0,0,0,0};
#pragma unroll
  for (int kc = 0; kc < 4; ++kc) {
    const float* p = hnewp + ((long)kc * 128 + b) * 512 + h0;
    s0 += *(const f32x4*)p;
    s1 += *(const f32x4*)(p + 4);
  }
  s0 += *(const f32x4*)(bsl + h0);
  s1 += *(const f32x4*)(bsl + h0 + 4);
  bf16x8 hb;
#pragma unroll
  for (int j = 0; j < 4; ++j) { hb[j] = (bf16)s0[j]; hb[4 + j] = (bf16)s1[j]; }
  *(bf16x8*)(hg + (long)b * 512 + h0) = hb;
  const float* wl = wlin + (long)t * 512 + h0;
  f32x4 w0 = *(const f32x4*)wl, w1 = *(const f32x4*)(wl + 4);
  float dot = s0[0]*w0[0] + s0[1]*w0[1] + s0[2]*w0[2] + s0[3]*w0[3]
            + s1[0]*w1[0] + s1[1]*w1[1] + s1[2]*w1[2] + s1[3]*w1[3];
  for (int d = 32; d > 0; d >>= 1) dot += __shfl_xor(dot, d, 64);
  if (lane == 0) out[t * 128 + b] = dot + blin[t];
}

// ------------------- fused kernels: LSTM(t) || chain(t-1) ------------------
#define LSTM_PARAMS const bf16* A0, long a0ss, const bf16* A1, const bf16* W, \
                    const float* bias, const float* csR, float* csW, bf16* hOut
#define LSTM_ARGS   A0, a0ss, A1, W, bias, csR, csW, hOut

__global__ __launch_bounds__(256, 4) void k_f0(int lb, LSTM_PARAMS,
    const bf16* hg, const bf16* hsC, const bf16* Wg, const float* bgp,
    const float* csC, bf16* icat, bf16* ccat)
{
  int bid = blockIdx.x;
  if (bid < lb) d_lstm(bid, threadIdx.x, LSTM_ARGS);
  else d_cell(bid - lb, threadIdx.x, hg, hsC, Wg, bgp, csC, icat, ccat);
}

__global__ __launch_bounds__(256, 4) void k_f1(int lb, LSTM_PARAMS,
    const bf16* icat, const bf16* ccat, const bf16* Wt, const float* bilc,
    float* t1s, float* t2s)
{
  int bid = blockIdx.x;
  if (bid < lb) d_lstm(bid, threadIdx.x, LSTM_ARGS);
  else d_tg(bid - lb, threadIdx.x, icat, ccat, Wt, bilc, t1s, t2s);
}

__global__ __launch_bounds__(256, 4) void k_f2(int lb, LSTM_PARAMS,
    const float* t1s, const float* t2s, bf16* cat)
{
  int bid = blockIdx.x;
  if (bid < lb) d_lstm(bid, threadIdx.x, LSTM_ARGS);
  else d_comb(bid - lb, threadIdx.x, t1s, t2s, cat);
}

__global__ __launch_bounds__(256, 4) void k_f3(int lb, LSTM_PARAMS,
    const bf16* cat, const bf16* Wsl, float* hnp)
{
  int bid = blockIdx.x;
  if (bid < lb) d_lstm(bid, threadIdx.x, LSTM_ARGS);
  else d_slg(bid - lb, threadIdx.x, cat, Wsl, hnp);
}

__global__ __launch_bounds__(256, 4) void k_f4(int lb, LSTM_PARAMS,
    const float* hnp, const float* bsl, const float* wlin, const float* blin,
    bf16* hg, float* out, int tc)
{
  int bid = blockIdx.x;
  if (bid < lb) d_lstm(bid, threadIdx.x, LSTM_ARGS);
  else d_fin(bid - lb, threadIdx.x, hnp, bsl, wlin, blin, hg, out, tc);
}

// ------------------------- weight conversion kernels -----------------------
__global__ __launch_bounds__(256) void cvt_wxh(const float* __restrict__ Wx,
    const float* __restrict__ Wh, bf16* __restrict__ dst)
{
  long idx = ((long)blockIdx.x * 256 + threadIdx.x) * 4;   // [al][n][k], n=4o+g
  int k = (int)(idx & 1023);
  int n = (int)((idx >> 10) & 2047);
  long al = idx >> 21;                                     // a*5+l
  int g = n & 3, o = n >> 2;
  const float* src = (k < 512)
      ? Wx + ((al * 4 + g) * 512 + o) * 512 + k
      : Wh + ((al * 4 + g) * 512 + o) * 512 + (k - 512);
  f32x4 v = *(const f32x4*)src;
  bf16x4 ov;
#pragma unroll
  for (int j = 0; j < 4; ++j) ov[j] = (bf16)v[j];
  *(bf16x4*)(dst + idx) = ov;
}

__global__ __launch_bounds__(256) void cvt_wg(const float* __restrict__ Wg_h,
    const float* __restrict__ Wg_p, bf16* __restrict__ dst)
{
  long idx = ((long)blockIdx.x * 256 + threadIdx.x) * 4;   // [la][n=4z+g][k], g==3 pad
  int k = (int)(idx & 1023);
  int n = (int)((idx >> 10) & 2047);
  long la = idx >> 21;                                     // l*3+a
  int g = n & 3, z = n >> 2;
  f32x4 v = {0, 0, 0, 0};
  if (g < 3) {
    const float* src = (k < 512)
        ? Wg_h + ((la * 3 + g) * 512 + z) * 512 + k
        : Wg_p + ((la * 3 + g) * 512 + z) * 512 + (k - 512);
    v = *(const f32x4*)src;
  }
  bf16x4 ov;
#pragma unroll
  for (int j = 0; j < 4; ++j) ov[j] = (bf16)v[j];
  *(bf16x4*)(dst + idx) = ov;
}

__global__ __launch_bounds__(256) void cvt_wt(const float* __restrict__ Wilc,
                                              bf16* __restrict__ dst)
{
  long idx = (long)blockIdx.x * 256 + threadIdx.x;         // [l][y][k=a*512+z]
  int k = (int)(idx % 1536);
  long rest = idx / 1536;
  int y = (int)(rest & 511);
  int l = (int)(rest >> 9);
  int a = k >> 9, z = k & 511;
  dst[idx] = (bf16)Wilc[(((long)l * 3 + a) * 512 + z) * 512 + y];
}

__global__ __launch_bounds__(256) void k_cast(const float* __restrict__ s,
                                              bf16* __restrict__ d)
{
  long i = ((long)blockIdx.x * 256 + threadIdx.x) * 4;
  f32x4 v = *(const f32x4*)(s + i);
  bf16x4 ov;
#pragma unroll
  for (int j = 0; j < 4; ++j) ov[j] = (bf16)v[j];
  *(bf16x4*)(d + i) = ov;
}

__global__ __launch_bounds__(256) void k_zero(uint4* __restrict__ p, long n)
{
  long i = (long)blockIdx.x * 256 + threadIdx.x;
  if (i < n) p[i] = make_uint4(0, 0, 0, 0);
}

// ---------------------------------------------------------------------------
extern "C" void kernel_launch(void* const* d_in, const int* in_sizes, int n_in,
                              void* d_out, int out_size, void* d_ws, size_t ws_size,
                              hipStream_t stream)
{
  const float* x    = (const float*)d_in[0];
  const float* Wx   = (const float*)d_in[1];
  const float* Wh   = (const float*)d_in[2];
  const float* b_l  = (const float*)d_in[3];
  const float* Wg_h = (const float*)d_in[4];
  const float* Wg_p = (const float*)d_in[5];
  const float* bg   = (const float*)d_in[6];
  const float* Wilc = (const float*)d_in[7];
  const float* bilc = (const float*)d_in[8];
  const float* Wsl  = (const float*)d_in[9];
  const float* bsl  = (const float*)d_in[10];
  const float* Wlin = (const float*)d_in[11];
  const float* blin = (const float*)d_in[12];
  float* out = (float*)d_out;

  char* w = (char*)d_ws;
  auto alloc = [&](long bytes) { char* p = w; w += (bytes + 255) & ~255L; return p; };
  bf16* Wcat = (bf16*)alloc(31457280L * 2);   // [a][l][2048][1024]
  bf16* Wg   = (bf16*)alloc(31457280L * 2);   // [l*3+a][2048][1024]
  bf16* Wt   = (bf16*)alloc(3932160L * 2);    // [l][512][1536]
  bf16* Wslb = (bf16*)alloc(1310720L * 2);    // [512][2560]
  bf16* xbf  = (bf16*)alloc(4194304L * 2);    // [t][b][512]
  char* zbase = w;
  bf16* hs0  = (bf16*)alloc(983040L * 2);     // [l][a][b][512] ping
  bf16* hs1  = (bf16*)alloc(983040L * 2);     // pong
  bf16* hgb  = (bf16*)alloc(65536L * 2);      // [b][512]
  float* cs0 = (float*)alloc(983040L * 4);    // [l][a][b][512] ping
  float* cs1 = (float*)alloc(983040L * 4);    // pong
  long zbytes = w - zbase;
  bf16* icat = (bf16*)alloc(983040L * 2);     // [l][b][1536]
  bf16* ccat = (bf16*)alloc(983040L * 2);
  float* t1s = (float*)alloc(327680L * 4);    // [l][b][512]
  float* t2s = (float*)alloc(327680L * 4);
  bf16* catb = (bf16*)alloc(327680L * 2);     // [b][2560]
  float* hnp = (float*)alloc(262144L * 4);    // [kc][b][512]
  (void)ws_size; (void)n_in; (void)in_sizes; (void)out_size;

  // --- setup (runs every call; ws is re-poisoned by the harness) ---
  cvt_wxh<<<30720, 256, 0, stream>>>(Wx, Wh, Wcat);
  cvt_wg <<<30720, 256, 0, stream>>>(Wg_h, Wg_p, Wg);
  cvt_wt <<<15360, 256, 0, stream>>>(Wilc, Wt);
  k_cast <<<1280,  256, 0, stream>>>(Wsl, Wslb);
  k_cast <<<4096,  256, 0, stream>>>(x, xbf);
  {
    long n16 = zbytes / 16;
    k_zero<<<(int)((n16 + 255) / 256), 256, 0, stream>>>((uint4*)zbase, n16);
  }

  // --- pipelined loop: LSTM level l of step t || chain stage l of step t-1 -
  for (int s = 0; s < 65; ++s) {
    const int t  = (s < 64) ? s : 63;       // lstm step (active iff s<64)
    const int tc = (s > 0) ? s - 1 : 0;     // chain step (active iff s>0)
    const int lb = (s < 64) ? 384 : 0;
    const int cb0 = (s > 0) ? 960 : 0, cb1 = (s > 0) ? 160 : 0,
              cb2 = (s > 0) ? 160 : 0, cb3 = (s > 0) ? 128 : 0,
              cb4 = (s > 0) ? 32 : 0;
    const bf16*  hsR = (t & 1) ? hs1 : hs0;
    bf16*        hsW = (t & 1) ? hs0 : hs1;
    const float* csR = (t & 1) ? cs1 : cs0;
    float*       csW = (t & 1) ? cs0 : cs1;
    const bf16*  hsC = (tc & 1) ? hs0 : hs1;   // = hsW(tc)
    const float* csC = (tc & 1) ? cs0 : cs1;   // = csW(tc)

#define LA(l) ((l) == 0 ? xbf + (long)t * 65536 : hsW + (long)((l) - 1) * 196608), \
              ((l) == 0 ? 0L : 65536L), \
              hsR + (long)(l) * 196608, Wcat + (long)(l) * 2097152, \
              b_l + (long)(l) * 2048, csR + (long)(l) * 196608, \
              csW + (long)(l) * 196608, hsW + (long)(l) * 196608

    k_f0<<<lb + cb0, 256, 0, stream>>>(lb, LA(0), hgb, hsC, Wg, bg, csC, icat, ccat);
    k_f1<<<lb + cb1, 256, 0, stream>>>(lb, LA(1), icat, ccat, Wt, bilc, t1s, t2s);
    k_f2<<<lb + cb2, 256, 0, stream>>>(lb, LA(2), t1s, t2s, catb);
    k_f3<<<lb + cb3, 256, 0, stream>>>(lb, LA(3), catb, Wslb, hnp);
    k_f4<<<lb + cb4, 256, 0, stream>>>(lb, LA(4), hnp, bsl, Wlin, blin, hgb, out, tc);
#undef LA
  }
}